// Round 6
// baseline (262.468 us; speedup 1.0000x reference)
//
#include <hip/hip_runtime.h>
#include <math.h>

#define BB 2
#define SS 2048
#define DM 1024
#define NH 16
#define HD 64

typedef __attribute__((ext_vector_type(8))) __bf16 bf16x8;
typedef __attribute__((ext_vector_type(4))) __bf16 bf16x4;
typedef __attribute__((ext_vector_type(8))) unsigned short u16x8;
typedef __attribute__((ext_vector_type(4))) float f32x4;
typedef unsigned short u16;
typedef unsigned int u32;
typedef __attribute__((address_space(1))) unsigned int u32g;
typedef __attribute__((address_space(3))) unsigned int u32l;

#define CEXP 0.18033688011112042f   // 0.125 * log2(e)

static __device__ __forceinline__ u16 f2bf(float f) {
    __bf16 h = (__bf16)f;
    return __builtin_bit_cast(unsigned short, h);
}

// async global->LDS, 16B/lane; lds base wave-uniform, lane i lands at base + i*16B
static __device__ __forceinline__ void gld16(const u16* g, u16* l) {
    __builtin_amdgcn_global_load_lds((const u32g*)g, (u32l*)l, 16, 0, 0);
}

// ---------------- fused fp32 -> bf16 cast for x + 4 weights ----------------
__global__ __launch_bounds__(256)
void cast_all(const float* __restrict__ x,
              const float* __restrict__ wq, const float* __restrict__ wk,
              const float* __restrict__ wv, const float* __restrict__ wo,
              u16* __restrict__ xb, u16* __restrict__ wqb, u16* __restrict__ wkb,
              u16* __restrict__ wvb, u16* __restrict__ wob)
{
    const int N4X = (BB * SS * DM) / 4;   // 1048576
    const int N4W = (DM * DM) / 4;        // 262144
    int i = blockIdx.x * 256 + threadIdx.x;
    const float* src; u16* dst; int off;
    if (i < N4X) { src = x; dst = xb; off = i; }
    else {
        int i2 = i - N4X;
        int w = i2 >> 18;
        off = i2 & (N4W - 1);
        switch (w) {
            case 0:  src = wq; dst = wqb; break;
            case 1:  src = wk; dst = wkb; break;
            case 2:  src = wv; dst = wvb; break;
            default: src = wo; dst = wob; break;
        }
    }
    float4 v = ((const float4*)src)[off];
    ushort4 o;
    o.x = f2bf(v.x); o.y = f2bf(v.y); o.z = f2bf(v.z); o.w = f2bf(v.w);
    ((ushort4*)dst)[off] = o;
}

// ---------------- QKV projection: BK=64 swizzled gld16; fp32 RoPE; transposed epilogue ------
// z==0/1 -> Q/K in [b,h,s,d]; z==2 -> V written TRANSPOSED [b,h,d,s] for attn direct reads.
__global__ __launch_bounds__(256, 3)
void qkv_gemm(const u16* __restrict__ X,
              const u16* __restrict__ Wq, const u16* __restrict__ Wk,
              const u16* __restrict__ Wv,
              const int* __restrict__ tp, const float* __restrict__ cosp,
              const float* __restrict__ sinp, const int* __restrict__ use_rope,
              u16* __restrict__ Q, u16* __restrict__ K, u16* __restrict__ V)
{
    const u16* W; u16* dst;
    if (blockIdx.z == 0)      { W = Wq; dst = Q; }
    else if (blockIdx.z == 1) { W = Wk; dst = K; }
    else                      { W = Wv; dst = V; }

    __shared__ u16 SH[4 * 64 * 68];   // 34816 B: {As,Bs} during k-loop; Ts after
    u16* As = SH;                     // 128 x 64
    u16* Bs = SH + 8192;              // 128 x 64
    const int t  = threadIdx.x;
    const int wv = t >> 6, L = t & 63, ln = L & 15, qd = L >> 4;
    const int i0 = blockIdx.y * 128, j0 = blockIdx.x * 128;
    const int wm = (wv >> 1) * 64, wn = (wv & 1) * 64;
    const int srow = L >> 3;
    const int scg  = ((L & 7) ^ (L >> 3)) * 8;

    f32x4 acc[4][4];
    #pragma unroll
    for (int a = 0; a < 4; ++a)
        #pragma unroll
        for (int b = 0; b < 4; ++b)
            #pragma unroll
            for (int e = 0; e < 4; ++e) acc[a][b][e] = 0.f;

    for (int k0 = 0; k0 < DM; k0 += 64) {
        __syncthreads();
        #pragma unroll
        for (int g = 0; g < 4; ++g) {
            int rb = wv * 32 + g * 8;
            gld16(X + (size_t)(i0 + rb + srow) * DM + k0 + scg, &As[rb * 64]);
            gld16(W + (size_t)(j0 + rb + srow) * DM + k0 + scg, &Bs[rb * 64]);
        }
        __syncthreads();
        bf16x8 a[4][2], b[4][2];
        #pragma unroll
        for (int mi = 0; mi < 4; ++mi)
            #pragma unroll
            for (int kd = 0; kd < 2; ++kd)
                a[mi][kd] = *(const bf16x8*)&As[(wm + mi * 16 + ln) * 64 + (((kd * 4 + qd) ^ (ln & 7)) * 8)];
        #pragma unroll
        for (int ni = 0; ni < 4; ++ni)
            #pragma unroll
            for (int kd = 0; kd < 2; ++kd)
                b[ni][kd] = *(const bf16x8*)&Bs[(wn + ni * 16 + ln) * 64 + (((kd * 4 + qd) ^ (ln & 7)) * 8)];
        #pragma unroll
        for (int kd = 0; kd < 2; ++kd)
            #pragma unroll
            for (int mi = 0; mi < 4; ++mi)
                #pragma unroll
                for (int ni = 0; ni < 4; ++ni)
                    acc[mi][ni] = __builtin_amdgcn_mfma_f32_16x16x32_bf16(a[mi][kd], b[ni][kd], acc[mi][ni], 0, 0, 0);
    }

    // ---- RoPE in fp32 on accumulators (lane pairs hold adjacent d) ----
    const int rope_on = (blockIdx.z < 2) ? use_rope[0] : 0;
    if (rope_on) {
        #pragma unroll
        for (int mi = 0; mi < 4; ++mi)
            #pragma unroll
            for (int r = 0; r < 4; ++r) {
                int gi = i0 + wm + mi * 16 + qd * 4 + r;
                int s = gi & 2047;
                int pos = tp[s];
                #pragma unroll
                for (int ni = 0; ni < 4; ++ni) {
                    int d = wn + ni * 16 + ln;
                    int dh = d & 63;
                    float c  = cosp[pos * 32 + (dh >> 1)];
                    float sn = sinp[pos * 32 + (dh >> 1)];
                    float v = acc[mi][ni][r];
                    float pv = __shfl_xor(v, 1);
                    acc[mi][ni][r] = (dh & 1) ? (v * c + pv * sn) : (v * c - pv * sn);
                }
            }
    }

    // ---- epilogue: per-wave LDS transpose ----
    __syncthreads();
    u16* Ts = SH + wv * (64 * 68);    // 64 rows (s) x 64 cols (d), stride 68
    #pragma unroll
    for (int mi = 0; mi < 4; ++mi)
        #pragma unroll
        for (int ni = 0; ni < 4; ++ni)
            #pragma unroll
            for (int r = 0; r < 4; ++r)
                Ts[(mi * 16 + qd * 4 + r) * 68 + ni * 16 + ln] = f2bf(acc[mi][ni][r]);

    const int h  = blockIdx.x * 2 + (wv & 1);
    const int sb = i0 + wm;
    const int b_ = sb >> 11, s0 = sb & 2047;
    if (blockIdx.z < 2) {
        // Q/K: [b,h,s,d] coalesced u16x8 rows
        const int lrow = L >> 3, lcol = (L & 7) * 8;
        #pragma unroll
        for (int r2 = 0; r2 < 8; ++r2) {
            int row = lrow + r2 * 8;
            u16x8 val = *(const u16x8*)&Ts[row * 68 + lcol];
            *(u16x8*)&dst[(((size_t)(b_ * NH + h)) * SS + s0 + row) * HD + lcol] = val;
        }
    } else {
        // V: transposed [b,h,d,s] (8 s per lane along the row)
        const int sch = (L & 7) * 8;      // s-chunk within the 64-row tile
        const int dr0 = L >> 3;           // d-row base
        #pragma unroll
        for (int r2 = 0; r2 < 8; ++r2) {
            int d = dr0 + r2 * 8;
            u16x8 val;
            #pragma unroll
            for (int u = 0; u < 8; ++u) val[u] = Ts[(sch + u) * 68 + d];
            *(u16x8*)&dst[(((size_t)(b_ * NH + h)) * HD + d) * SS + s0 + sch] = val;
        }
    }
}

// ---------------- output projection: 128x128 tile, 8 waves, fp32 transposed epilogue ----
__global__ __launch_bounds__(512, 2)
void out_gemm(const u16* __restrict__ X, const u16* __restrict__ W,
              float* __restrict__ dst)
{
    __shared__ char SHB[73728];       // {As 16K, Bs 16K} k-loop; Ts 72K epilogue
    u16* As = (u16*)SHB;              // 128 x 64
    u16* Bs = (u16*)SHB + 8192;       // 128 x 64
    const int t  = threadIdx.x;
    const int wv = t >> 6, L = t & 63, ln = L & 15, qd = L >> 4;
    const int i0 = blockIdx.y * 128, j0 = blockIdx.x * 128;
    const int wm = (wv >> 2) * 64, wn = (wv & 3) * 32;   // 2x4 wave grid, 64x32 each
    const int srow = L >> 3;
    const int scg  = ((L & 7) ^ (L >> 3)) * 8;

    f32x4 acc[4][2];
    #pragma unroll
    for (int mi = 0; mi < 4; ++mi)
        #pragma unroll
        for (int ni = 0; ni < 2; ++ni)
            #pragma unroll
            for (int e = 0; e < 4; ++e) acc[mi][ni][e] = 0.f;

    for (int k0 = 0; k0 < DM; k0 += 64) {
        __syncthreads();
        #pragma unroll
        for (int g = 0; g < 2; ++g) {
            int rb = wv * 16 + g * 8;
            gld16(X + (size_t)(i0 + rb + srow) * DM + k0 + scg, &As[rb * 64]);
            gld16(W + (size_t)(j0 + rb + srow) * DM + k0 + scg, &Bs[rb * 64]);
        }
        __syncthreads();
        bf16x8 a[4][2], b[2][2];
        #pragma unroll
        for (int mi = 0; mi < 4; ++mi)
            #pragma unroll
            for (int kd = 0; kd < 2; ++kd)
                a[mi][kd] = *(const bf16x8*)&As[(wm + mi * 16 + ln) * 64 + (((kd * 4 + qd) ^ (ln & 7)) * 8)];
        #pragma unroll
        for (int ni = 0; ni < 2; ++ni)
            #pragma unroll
            for (int kd = 0; kd < 2; ++kd)
                b[ni][kd] = *(const bf16x8*)&Bs[(wn + ni * 16 + ln) * 64 + (((kd * 4 + qd) ^ (ln & 7)) * 8)];
        #pragma unroll
        for (int kd = 0; kd < 2; ++kd)
            #pragma unroll
            for (int mi = 0; mi < 4; ++mi)
                #pragma unroll
                for (int ni = 0; ni < 2; ++ni)
                    acc[mi][ni] = __builtin_amdgcn_mfma_f32_16x16x32_bf16(a[mi][kd], b[ni][kd], acc[mi][ni], 0, 0, 0);
    }

    __syncthreads();
    float* Ts = (float*)SHB + wv * (64 * 36);   // per-wave 64 rows x 32 cols, stride 36
    #pragma unroll
    for (int mi = 0; mi < 4; ++mi)
        #pragma unroll
        for (int ni = 0; ni < 2; ++ni)
            #pragma unroll
            for (int r = 0; r < 4; ++r)
                Ts[(mi * 16 + qd * 4 + r) * 36 + ni * 16 + ln] = acc[mi][ni][r];

    const int lrow = L >> 3, lch = L & 7;
    #pragma unroll
    for (int r2 = 0; r2 < 8; ++r2) {
        int row = lrow + r2 * 8;
        float4 v = *(const float4*)&Ts[row * 36 + lch * 4];
        *(float4*)&dst[(size_t)(i0 + wm + row) * DM + j0 + wn + lch * 4] = v;
    }
}

// ---------------- barrier-free flash attention: L2-direct K/V, per-wave strips ----
// Each wave owns a 16-row q-strip; K/V fragments read directly from L2 (KV per bh
// = 512 KB; bh%8 -> fixed XCD -> 2 MB hot set per 4 MB L2). No staging, no double
// buffers, no per-tile barriers: 16 fully decorrelated waves/CU. Equal duration via
// in-wave split-K pairing: phase1 = (strip s, lower key-half), phase2 =
// (strip 127-s, upper half incl diagonal) -> every wave 16-17 tile-steps. One
// __syncthreads; partner waves (3-wv) merge flash states through swizzled LDS.
static __device__ __forceinline__ void attn_tile(
    const u16* __restrict__ Kp, const u16* __restrict__ Vp,
    bf16x8 qf0, bf16x8 qf1, u16* psw,
    int j0, bool diag, int rowg, int ln, int qd,
    float& m, float& l, f32x4* o)
{
    const int pm = 2 * (ln & 7);     // even XOR mask over 8B granules (Ps swizzle)
    f32x4 s[4];
    const u16* kb = Kp + (size_t)(j0 + ln) * HD + qd * 8;
    #pragma unroll
    for (int mt = 0; mt < 4; ++mt) {
        bf16x8 a0 = *(const bf16x8*)(kb + mt * 16 * HD);
        bf16x8 a1 = *(const bf16x8*)(kb + mt * 16 * HD + 32);
        s[mt][0] = s[mt][1] = s[mt][2] = s[mt][3] = 0.f;
        s[mt] = __builtin_amdgcn_mfma_f32_16x16x32_bf16(a0, qf0, s[mt], 0, 0, 0);
        s[mt] = __builtin_amdgcn_mfma_f32_16x16x32_bf16(a1, qf1, s[mt], 0, 0, 0);
    }
    if (diag) {
        #pragma unroll
        for (int mt = 0; mt < 4; ++mt)
            #pragma unroll
            for (int r = 0; r < 4; ++r)
                if (j0 + mt * 16 + qd * 4 + r > rowg) s[mt][r] = -3.0e38f;
    }

    // ---- speculative P with OLD max (ILP-overlaps the reduce) ----
    float p[16];
    float nmc = m * CEXP;
    #pragma unroll
    for (int mt = 0; mt < 4; ++mt)
        #pragma unroll
        for (int r = 0; r < 4; ++r)
            p[mt * 4 + r] = exp2f(fmaf(s[mt][r], CEXP, -nmc));

    float rm = s[0][0];
    #pragma unroll
    for (int mt = 0; mt < 4; ++mt)
        #pragma unroll
        for (int r = 0; r < 4; ++r) rm = fmaxf(rm, s[mt][r]);
    rm = fmaxf(rm, __shfl_xor(rm, 16));
    rm = fmaxf(rm, __shfl_xor(rm, 32));

    // ---- slow path only when max grows materially (P bounded by 2^8) ----
    if (__any((rm - m) * CEXP > 8.0f)) {
        float nm = fmaxf(m, rm);
        float alpha = exp2f((m - nm) * CEXP);   // ==0 on first tile (m=-inf): l,o zeroed
        nmc = nm * CEXP;
        #pragma unroll
        for (int mt = 0; mt < 4; ++mt)
            #pragma unroll
            for (int r = 0; r < 4; ++r)
                p[mt * 4 + r] = exp2f(fmaf(s[mt][r], CEXP, -nmc));
        #pragma unroll
        for (int ni = 0; ni < 4; ++ni)
            #pragma unroll
            for (int r = 0; r < 4; ++r) o[ni][r] *= alpha;
        l *= alpha;
        m = nm;
    }

    // ---- pack + per-wave LDS round-trip + row sum (wave-local lgkm only) ----
    float rs = 0.f;
    #pragma unroll
    for (int mt = 0; mt < 4; ++mt) {
        bf16x4 pk;
        #pragma unroll
        for (int r = 0; r < 4; ++r) {
            rs += p[mt * 4 + r];
            pk[r] = (__bf16)p[mt * 4 + r];
        }
        *(bf16x4*)(psw + ln * 64 + ((mt * 4 + qd) ^ pm) * 4) = pk;
    }
    rs += __shfl_xor(rs, 16);
    rs += __shfl_xor(rs, 32);
    l += rs;
    bf16x8 pf0 = *(const bf16x8*)(psw + ln * 64 + ((qd * 2) ^ pm) * 4);
    bf16x8 pf1 = *(const bf16x8*)(psw + ln * 64 + ((8 + qd * 2) ^ pm) * 4);

    // ---- PV: O^T += V^T x P, V fragments straight from L2 ----
    const u16* vb = Vp + (size_t)ln * SS + j0 + qd * 8;
    #pragma unroll
    for (int ni = 0; ni < 4; ++ni) {
        bf16x8 vf0 = *(const bf16x8*)(vb + (size_t)(ni * 16) * SS);
        bf16x8 vf1 = *(const bf16x8*)(vb + (size_t)(ni * 16) * SS + 32);
        o[ni] = __builtin_amdgcn_mfma_f32_16x16x32_bf16(vf0, pf0, o[ni], 0, 0, 0);
        o[ni] = __builtin_amdgcn_mfma_f32_16x16x32_bf16(vf1, pf1, o[ni], 0, 0, 0);
    }
}

__global__ __launch_bounds__(256, 4)
void attn_kernel(const u16* __restrict__ Q, const u16* __restrict__ K,
                 const u16* __restrict__ V, u16* __restrict__ Y)
{
    __shared__ u16  Ps[4][16 * 64];      // per-wave P round-trip, granule-swizzled (8 KB)
    __shared__ float MO[4][16 * 64];     // phase-1 O^T dump, granule-swizzled (16 KB)
    __shared__ float ML[4][32];          // m[16], l[16] per wave

    const int t  = threadIdx.x;
    const int wv = t >> 6, L = t & 63, ln = L & 15, qd = L >> 4;
    const int bh = blockIdx.x, b2 = blockIdx.y;
    const int b  = bh >> 4, h = bh & 15;
    const u16* Qp = Q + (size_t)bh * SS * HD;
    const u16* Kp = K + (size_t)bh * SS * HD;
    const u16* Vp = V + (size_t)bh * HD * SS;   // transposed [d][s]

    // strips per block: {2b2, 2b2+1, 126-2b2, 127-2b2}; partner pairs (0,3),(1,2)
    const int s1 = (wv == 0) ? 2 * b2 : (wv == 1) ? 2 * b2 + 1
                 : (wv == 2) ? 126 - 2 * b2 : 127 - 2 * b2;
    const int s2 = 127 - s1;
    const int T1 = (s1 >> 2) + 1, T2 = (s2 >> 2) + 1;

    u16* psw = &Ps[wv][0];
    float m, l;
    f32x4 o[4];

    // ---------------- phase 1: strip s1, key tiles [0, T1/2)  (never diagonal) ----
    {
        const int qb = s1 * 16;
        const u16* rq = Qp + (size_t)(qb + ln) * HD;
        bf16x8 qf0 = *(const bf16x8*)(rq + qd * 8);
        bf16x8 qf1 = *(const bf16x8*)(rq + 32 + qd * 8);
        m = -3.0e38f; l = 0.f;
        #pragma unroll
        for (int ni = 0; ni < 4; ++ni)
            o[ni][0] = o[ni][1] = o[ni][2] = o[ni][3] = 0.f;
        const int e1 = T1 >> 1;
        #pragma unroll 1
        for (int tix = 0; tix < e1; ++tix)
            attn_tile(Kp, Vp, qf0, qf1, psw, tix * 64, false, qb + ln, ln, qd, m, l, o);
        // dump phase-1 state (bank-swizzled: granule ^ ln)
        if (qd == 0) { ML[wv][ln] = m; ML[wv][16 + ln] = l; }
        #pragma unroll
        for (int ni = 0; ni < 4; ++ni)
            *(f32x4*)&MO[wv][ln * 64 + (((ni * 4 + qd) ^ ln) * 4)] = o[ni];
    }

    // ---------------- phase 2: strip s2, key tiles [T2/2, T2) (incl diagonal) ----
    {
        const int qb = s2 * 16;
        const u16* rq = Qp + (size_t)(qb + ln) * HD;
        bf16x8 qf0 = *(const bf16x8*)(rq + qd * 8);
        bf16x8 qf1 = *(const bf16x8*)(rq + 32 + qd * 8);
        m = -3.0e38f; l = 0.f;                 // slow path zeroes o on first tile
        #pragma unroll 1
        for (int tix = T2 >> 1; tix < T2; ++tix)
            attn_tile(Kp, Vp, qf0, qf1, psw, tix * 64, tix == T2 - 1, qb + ln, ln, qd, m, l, o);
    }

    __syncthreads();   // the ONLY block-wide barrier

    // ---------------- merge partner's phase-1 (same strip s2) + epilogue ----
    {
        const int pw = 3 - wv;                 // partner wave: its s1 == my s2
        float mp = ML[pw][ln], lp = ML[pw][16 + ln];
        float mf = fmaxf(m, mp);
        float as = exp2f((m - mf) * CEXP);
        float ap = exp2f((mp - mf) * CEXP);
        float lf = as * l + ap * lp;
        float inv = 1.f / lf;
        const int sq = s2 * 16 + ln;
        #pragma unroll
        for (int ni = 0; ni < 4; ++ni) {
            f32x4 op = *(const f32x4*)&MO[pw][ln * 64 + (((ni * 4 + qd) ^ ln) * 4)];
            bf16x4 pk;
            #pragma unroll
            for (int r = 0; r < 4; ++r)
                pk[r] = (__bf16)((as * o[ni][r] + ap * op[r]) * inv);
            *(bf16x4*)&Y[((size_t)(b * SS + sq)) * DM + h * HD + ni * 16 + qd * 4] = pk;
        }
    }
}

extern "C" void kernel_launch(void* const* d_in, const int* in_sizes, int n_in,
                              void* d_out, int out_size, void* d_ws, size_t ws_size,
                              hipStream_t stream)
{
    const float* x        = (const float*)d_in[0];
    const int*   tp       = (const int*)d_in[1];
    const int*   use_rope = (const int*)d_in[2];
    const float* Wq       = (const float*)d_in[3];
    const float* Wk       = (const float*)d_in[4];
    const float* Wv       = (const float*)d_in[5];
    const float* Wo       = (const float*)d_in[6];
    const float* cosp     = (const float*)d_in[7];
    const float* sinp     = (const float*)d_in[8];
    float* out = (float*)d_out;

    char* ws = (char*)d_ws;
    const size_t MB = 1 << 20;
    u16* xb  = (u16*)(ws);
    u16* Wqb = (u16*)(ws + 8 * MB);
    u16* Wkb = (u16*)(ws + 10 * MB);
    u16* Wvb = (u16*)(ws + 12 * MB);
    u16* Wob = (u16*)(ws + 14 * MB);
    u16* Qb  = (u16*)(ws + 16 * MB);
    u16* Kb  = (u16*)(ws + 24 * MB);
    u16* Vb  = (u16*)(ws + 32 * MB);
    u16* Yb  = (u16*)(ws + 40 * MB);

    cast_all<<<8192, 256, 0, stream>>>(x, Wq, Wk, Wv, Wo, xb, Wqb, Wkb, Wvb, Wob);
    qkv_gemm<<<dim3(DM / 128, BB * SS / 128, 3), 256, 0, stream>>>(
        xb, Wqb, Wkb, Wvb, tp, cosp, sinp, use_rope, Qb, Kb, Vb);
    attn_kernel<<<dim3(BB * NH, 32), 256, 0, stream>>>(Qb, Kb, Vb, Yb);
    out_gemm<<<dim3(DM / 128, BB * SS / 128), 512, 0, stream>>>(Yb, Wob, out);
}

// Round 7
// 188.968 us; speedup vs baseline: 1.3890x; 1.3890x over previous
//
#include <hip/hip_runtime.h>
#include <math.h>

#define BB 2
#define SS 2048
#define DM 1024
#define NH 16
#define HD 64

typedef __attribute__((ext_vector_type(8))) __bf16 bf16x8;
typedef __attribute__((ext_vector_type(4))) __bf16 bf16x4;
typedef __attribute__((ext_vector_type(8))) unsigned short u16x8;
typedef __attribute__((ext_vector_type(4))) float f32x4;
typedef __attribute__((ext_vector_type(4))) unsigned int u32x4;
typedef unsigned short u16;
typedef unsigned int u32;
typedef __attribute__((address_space(1))) unsigned int u32g;
typedef __attribute__((address_space(3))) unsigned int u32l;

#define CEXP 0.18033688011112042f   // 0.125 * log2(e)

static __device__ __forceinline__ u16 f2bf(float f) {
    __bf16 h = (__bf16)f;
    return __builtin_bit_cast(unsigned short, h);
}

static __device__ __forceinline__ u32 pk2(float a, float b) {
    u32 lo = (u32)f2bf(a), hi = (u32)f2bf(b);
    return lo | (hi << 16);
}

// async global->LDS, 16B/lane; lds base wave-uniform, lane i lands at base + i*16B
static __device__ __forceinline__ void gld16(const u16* g, u16* l) {
    __builtin_amdgcn_global_load_lds((const u32g*)g, (u32l*)l, 16, 0, 0);
}

// ---------------- fused fp32 -> bf16 cast for x + 4 weights ----------------
__global__ __launch_bounds__(256)
void cast_all(const float* __restrict__ x,
              const float* __restrict__ wq, const float* __restrict__ wk,
              const float* __restrict__ wv, const float* __restrict__ wo,
              u16* __restrict__ xb, u16* __restrict__ wqb, u16* __restrict__ wkb,
              u16* __restrict__ wvb, u16* __restrict__ wob)
{
    const int N4X = (BB * SS * DM) / 4;   // 1048576
    const int N4W = (DM * DM) / 4;        // 262144
    int i = blockIdx.x * 256 + threadIdx.x;
    const float* src; u16* dst; int off;
    if (i < N4X) { src = x; dst = xb; off = i; }
    else {
        int i2 = i - N4X;
        int w = i2 >> 18;
        off = i2 & (N4W - 1);
        switch (w) {
            case 0:  src = wq; dst = wqb; break;
            case 1:  src = wk; dst = wkb; break;
            case 2:  src = wv; dst = wvb; break;
            default: src = wo; dst = wob; break;
        }
    }
    float4 v = ((const float4*)src)[off];
    ushort4 o;
    o.x = f2bf(v.x); o.y = f2bf(v.y); o.z = f2bf(v.z); o.w = f2bf(v.w);
    ((ushort4*)dst)[off] = o;
}

// ---------------- QKV projection: BK=64 swizzled gld16; fp32 RoPE; transposed epilogue ------
// z==0/1 -> Q/K in [b,h,s,d]; z==2 -> V written TRANSPOSED [b,h,d,s], direct from acc.
__global__ __launch_bounds__(256, 3)
void qkv_gemm(const u16* __restrict__ X,
              const u16* __restrict__ Wq, const u16* __restrict__ Wk,
              const u16* __restrict__ Wv,
              const int* __restrict__ tp, const float* __restrict__ cosp,
              const float* __restrict__ sinp, const int* __restrict__ use_rope,
              u16* __restrict__ Q, u16* __restrict__ K, u16* __restrict__ V)
{
    const u16* W; u16* dst;
    if (blockIdx.z == 0)      { W = Wq; dst = Q; }
    else if (blockIdx.z == 1) { W = Wk; dst = K; }
    else                      { W = Wv; dst = V; }

    __shared__ u16 SH[4 * 64 * 68];   // 34816 B: {As,Bs} during k-loop; Ts after (z<2)
    u16* As = SH;                     // 128 x 64
    u16* Bs = SH + 8192;              // 128 x 64
    const int t  = threadIdx.x;
    const int wv = t >> 6, L = t & 63, ln = L & 15, qd = L >> 4;
    const int i0 = blockIdx.y * 128, j0 = blockIdx.x * 128;
    const int wm = (wv >> 1) * 64, wn = (wv & 1) * 64;
    const int srow = L >> 3;
    const int scg  = ((L & 7) ^ (L >> 3)) * 8;

    f32x4 acc[4][4];
    #pragma unroll
    for (int a = 0; a < 4; ++a)
        #pragma unroll
        for (int b = 0; b < 4; ++b)
            #pragma unroll
            for (int e = 0; e < 4; ++e) acc[a][b][e] = 0.f;

    for (int k0 = 0; k0 < DM; k0 += 64) {
        __syncthreads();
        #pragma unroll
        for (int g = 0; g < 4; ++g) {
            int rb = wv * 32 + g * 8;
            gld16(X + (size_t)(i0 + rb + srow) * DM + k0 + scg, &As[rb * 64]);
            gld16(W + (size_t)(j0 + rb + srow) * DM + k0 + scg, &Bs[rb * 64]);
        }
        __syncthreads();
        bf16x8 a[4][2], b[4][2];
        #pragma unroll
        for (int mi = 0; mi < 4; ++mi)
            #pragma unroll
            for (int kd = 0; kd < 2; ++kd)
                a[mi][kd] = *(const bf16x8*)&As[(wm + mi * 16 + ln) * 64 + (((kd * 4 + qd) ^ (ln & 7)) * 8)];
        #pragma unroll
        for (int ni = 0; ni < 4; ++ni)
            #pragma unroll
            for (int kd = 0; kd < 2; ++kd)
                b[ni][kd] = *(const bf16x8*)&Bs[(wn + ni * 16 + ln) * 64 + (((kd * 4 + qd) ^ (ln & 7)) * 8)];
        #pragma unroll
        for (int kd = 0; kd < 2; ++kd)
            #pragma unroll
            for (int mi = 0; mi < 4; ++mi)
                #pragma unroll
                for (int ni = 0; ni < 4; ++ni)
                    acc[mi][ni] = __builtin_amdgcn_mfma_f32_16x16x32_bf16(a[mi][kd], b[ni][kd], acc[mi][ni], 0, 0, 0);
    }

    // ---- RoPE in fp32 on accumulators (lane pairs hold adjacent d) ----
    const int rope_on = (blockIdx.z < 2) ? use_rope[0] : 0;
    if (rope_on) {
        #pragma unroll
        for (int mi = 0; mi < 4; ++mi)
            #pragma unroll
            for (int r = 0; r < 4; ++r) {
                int gi = i0 + wm + mi * 16 + qd * 4 + r;
                int s = gi & 2047;
                int pos = tp[s];
                #pragma unroll
                for (int ni = 0; ni < 4; ++ni) {
                    int d = wn + ni * 16 + ln;
                    int dh = d & 63;
                    float c  = cosp[pos * 32 + (dh >> 1)];
                    float sn = sinp[pos * 32 + (dh >> 1)];
                    float v = acc[mi][ni][r];
                    float pv = __shfl_xor(v, 1);
                    acc[mi][ni][r] = (dh & 1) ? (v * c + pv * sn) : (v * c - pv * sn);
                }
            }
    }

    const int h  = blockIdx.x * 2 + (wv & 1);
    const int sb = i0 + wm;
    const int b_ = sb >> 11, s0 = sb & 2047;
    if (blockIdx.z < 2) {
        // ---- epilogue: per-wave LDS transpose, Q/K [b,h,s,d] coalesced rows ----
        __syncthreads();
        u16* Ts = SH + wv * (64 * 68);    // 64 rows (s) x 64 cols (d), stride 68
        #pragma unroll
        for (int mi = 0; mi < 4; ++mi)
            #pragma unroll
            for (int ni = 0; ni < 4; ++ni)
                #pragma unroll
                for (int r = 0; r < 4; ++r)
                    Ts[(mi * 16 + qd * 4 + r) * 68 + ni * 16 + ln] = f2bf(acc[mi][ni][r]);

        const int lrow = L >> 3, lcol = (L & 7) * 8;
        #pragma unroll
        for (int r2 = 0; r2 < 8; ++r2) {
            int row = lrow + r2 * 8;
            u16x8 val = *(const u16x8*)&Ts[row * 68 + lcol];
            *(u16x8*)&dst[(((size_t)(b_ * NH + h)) * SS + s0 + row) * HD + lcol] = val;
        }
    } else {
        // ---- V: direct transposed store [b,h,d,s] from acc (4 consecutive s per
        // thread at fixed d) — no LDS transpose, no barrier ----
        #pragma unroll
        for (int mi = 0; mi < 4; ++mi)
            #pragma unroll
            for (int ni = 0; ni < 4; ++ni) {
                bf16x4 pk;
                #pragma unroll
                for (int r = 0; r < 4; ++r) pk[r] = (__bf16)acc[mi][ni][r];
                *(bf16x4*)&dst[(((size_t)(b_ * NH + h)) * HD + ni * 16 + ln) * SS
                               + s0 + mi * 16 + qd * 4] = pk;
            }
    }
}

// ---------------- output projection: 128x128 tile, 8 waves, fp32 transposed epilogue ----
__global__ __launch_bounds__(512, 2)
void out_gemm(const u16* __restrict__ X, const u16* __restrict__ W,
              float* __restrict__ dst)
{
    __shared__ char SHB[73728];       // {As 16K, Bs 16K} k-loop; Ts 72K epilogue
    u16* As = (u16*)SHB;              // 128 x 64
    u16* Bs = (u16*)SHB + 8192;       // 128 x 64
    const int t  = threadIdx.x;
    const int wv = t >> 6, L = t & 63, ln = L & 15, qd = L >> 4;
    const int i0 = blockIdx.y * 128, j0 = blockIdx.x * 128;
    const int wm = (wv >> 2) * 64, wn = (wv & 3) * 32;   // 2x4 wave grid, 64x32 each
    const int srow = L >> 3;
    const int scg  = ((L & 7) ^ (L >> 3)) * 8;

    f32x4 acc[4][2];
    #pragma unroll
    for (int mi = 0; mi < 4; ++mi)
        #pragma unroll
        for (int ni = 0; ni < 2; ++ni)
            #pragma unroll
            for (int e = 0; e < 4; ++e) acc[mi][ni][e] = 0.f;

    for (int k0 = 0; k0 < DM; k0 += 64) {
        __syncthreads();
        #pragma unroll
        for (int g = 0; g < 2; ++g) {
            int rb = wv * 16 + g * 8;
            gld16(X + (size_t)(i0 + rb + srow) * DM + k0 + scg, &As[rb * 64]);
            gld16(W + (size_t)(j0 + rb + srow) * DM + k0 + scg, &Bs[rb * 64]);
        }
        __syncthreads();
        bf16x8 a[4][2], b[2][2];
        #pragma unroll
        for (int mi = 0; mi < 4; ++mi)
            #pragma unroll
            for (int kd = 0; kd < 2; ++kd)
                a[mi][kd] = *(const bf16x8*)&As[(wm + mi * 16 + ln) * 64 + (((kd * 4 + qd) ^ (ln & 7)) * 8)];
        #pragma unroll
        for (int ni = 0; ni < 2; ++ni)
            #pragma unroll
            for (int kd = 0; kd < 2; ++kd)
                b[ni][kd] = *(const bf16x8*)&Bs[(wn + ni * 16 + ln) * 64 + (((kd * 4 + qd) ^ (ln & 7)) * 8)];
        #pragma unroll
        for (int kd = 0; kd < 2; ++kd)
            #pragma unroll
            for (int mi = 0; mi < 4; ++mi)
                #pragma unroll
                for (int ni = 0; ni < 2; ++ni)
                    acc[mi][ni] = __builtin_amdgcn_mfma_f32_16x16x32_bf16(a[mi][kd], b[ni][kd], acc[mi][ni], 0, 0, 0);
    }

    __syncthreads();
    float* Ts = (float*)SHB + wv * (64 * 36);   // per-wave 64 rows x 32 cols, stride 36
    #pragma unroll
    for (int mi = 0; mi < 4; ++mi)
        #pragma unroll
        for (int ni = 0; ni < 2; ++ni)
            #pragma unroll
            for (int r = 0; r < 4; ++r)
                Ts[(mi * 16 + qd * 4 + r) * 36 + ni * 16 + ln] = acc[mi][ni][r];

    const int lrow = L >> 3, lch = L & 7;
    #pragma unroll
    for (int r2 = 0; r2 < 8; ++r2) {
        int row = lrow + r2 * 8;
        float4 v = *(const float4*)&Ts[row * 36 + lch * 4];
        *(float4*)&dst[(size_t)(i0 + wm + row) * DM + j0 + wn + lch * 4] = v;
    }
}

// ---------------- MFMA flash attention: wave-specialized pairs, O^T accumulation ----
// Round-5 structure (best measured base) with the Ps LDS round-trip replaced by
// in-register P redistribution (pack bf16 pairs + 16 ds_bpermute + selects).
// Lane (ln,qd) holds P[key=mt*16+qd*4+r][q=ln]; PV B-frag needs P[keys qd*8..+7][q=ln]:
// word j of pf0 <- lane ln+32*(qd&1)+16*(j>>1), reg Wp[(qd>>1)][j&1] (pf1: +2).
static __device__ __forceinline__ void group_step(
    const u16* KsB, const bf16x8 qf[2],
    bool diag, int rowg, int j0, int ln, int qd, int srcA,
    float& m, float& l, bf16x8& pf0, bf16x8& pf1)
{
    f32x4 s[4];
    __builtin_amdgcn_s_setprio(1);
    #pragma unroll
    for (int mt = 0; mt < 4; ++mt) {
        bf16x8 a0 = *(const bf16x8*)&KsB[(mt * 16 + ln) * 64 + ((qd ^ (ln & 7)) * 8)];
        bf16x8 a1 = *(const bf16x8*)&KsB[(mt * 16 + ln) * 64 + (((4 + qd) ^ (ln & 7)) * 8)];
        #pragma unroll
        for (int e = 0; e < 4; ++e) s[mt][e] = 0.f;
        s[mt] = __builtin_amdgcn_mfma_f32_16x16x32_bf16(a0, qf[0], s[mt], 0, 0, 0);
        s[mt] = __builtin_amdgcn_mfma_f32_16x16x32_bf16(a1, qf[1], s[mt], 0, 0, 0);
    }
    __builtin_amdgcn_s_setprio(0);
    if (diag) {
        #pragma unroll
        for (int mt = 0; mt < 4; ++mt)
            #pragma unroll
            for (int r = 0; r < 4; ++r)
                if (j0 + mt * 16 + qd * 4 + r > rowg) s[mt][r] = -3.0e38f;
    }

    // ---- speculative P with OLD max (overlaps the reduce below via ILP) ----
    float p[16];
    float nmc = m * CEXP;
    #pragma unroll
    for (int mt = 0; mt < 4; ++mt)
        #pragma unroll
        for (int r = 0; r < 4; ++r)
            p[mt * 4 + r] = exp2f(fmaf(s[mt][r], CEXP, -nmc));

    // ---- row max (per-lane q) ----
    float rm = s[0][0];
    #pragma unroll
    for (int mt = 0; mt < 4; ++mt)
        #pragma unroll
        for (int r = 0; r < 4; ++r) rm = fmaxf(rm, s[mt][r]);
    rm = fmaxf(rm, __shfl_xor(rm, 16));
    rm = fmaxf(rm, __shfl_xor(rm, 32));

    // ---- slow path only when max grows materially (P bounded by 2^8) ----
    if (__any((rm - m) * CEXP > 8.0f)) {
        float nm = fmaxf(m, rm);
        float alpha = exp2f((m - nm) * CEXP);   // ==0 on first tile (m=-inf): l zeroed
        nmc = nm * CEXP;
        #pragma unroll
        for (int mt = 0; mt < 4; ++mt)
            #pragma unroll
            for (int r = 0; r < 4; ++r)
                p[mt * 4 + r] = exp2f(fmaf(s[mt][r], CEXP, -nmc));
        l *= alpha;
        m = nm;
    }

    // ---- pack P pairs + in-register redistribution (no LDS) + row sum ----
    u32 P00 = pk2(p[0],  p[1]),  P01 = pk2(p[2],  p[3]);
    u32 P10 = pk2(p[4],  p[5]),  P11 = pk2(p[6],  p[7]);
    u32 P20 = pk2(p[8],  p[9]),  P21 = pk2(p[10], p[11]);
    u32 P30 = pk2(p[12], p[13]), P31 = pk2(p[14], p[15]);
    const int srcB = srcA + 16;
    int a00 = __shfl((int)P00, srcA), a10 = __shfl((int)P10, srcA);
    int a01 = __shfl((int)P01, srcA), a11 = __shfl((int)P11, srcA);
    int b00 = __shfl((int)P00, srcB), b10 = __shfl((int)P10, srcB);
    int b01 = __shfl((int)P01, srcB), b11 = __shfl((int)P11, srcB);
    int a20 = __shfl((int)P20, srcA), a30 = __shfl((int)P30, srcA);
    int a21 = __shfl((int)P21, srcA), a31 = __shfl((int)P31, srcA);
    int b20 = __shfl((int)P20, srcB), b30 = __shfl((int)P30, srcB);
    int b21 = __shfl((int)P21, srcB), b31 = __shfl((int)P31, srcB);

    float rs = 0.f;
    #pragma unroll
    for (int i = 0; i < 16; ++i) rs += p[i];
    rs += __shfl_xor(rs, 16);
    rs += __shfl_xor(rs, 32);
    l += rs;

    const bool hi2 = (qd >> 1) != 0;    // selects Wp[1]/Wp[3] for qd in {2,3}
    u32x4 f0, f1;
    f0[0] = (u32)(hi2 ? a10 : a00); f0[1] = (u32)(hi2 ? a11 : a01);
    f0[2] = (u32)(hi2 ? b10 : b00); f0[3] = (u32)(hi2 ? b11 : b01);
    f1[0] = (u32)(hi2 ? a30 : a20); f1[1] = (u32)(hi2 ? a31 : a21);
    f1[2] = (u32)(hi2 ? b30 : b20); f1[3] = (u32)(hi2 ? b31 : b21);
    pf0 = __builtin_bit_cast(bf16x8, f0);
    pf1 = __builtin_bit_cast(bf16x8, f1);
}

__global__ __launch_bounds__(512, 4)
void attn_kernel(const u16* __restrict__ Q, const u16* __restrict__ K,
                 const u16* __restrict__ V, u16* __restrict__ Y)
{
    __shared__ u16 Ks[2][64 * 64];     // [key][d], gld16 source-swizzled, double-buffered
    __shared__ u16 Vt[2][64 * 64];     // [d][key] from global V^T, gld16, double-buffered

    const int t  = threadIdx.x;
    const int wv = t >> 6, L = t & 63, ln = L & 15, qd = L >> 4;
    const int wsub = wv & 3, grp = wv >> 2;
    const int bh = blockIdx.x;
    // complementary-duration remap: round-robin gives CU c blocks y and y+8 ->
    // p + p' = 15 -> every CU totals exactly 49 tile-iterations.
    const int y = blockIdx.y;
    const int p = (y < 8) ? y : (23 - y);
    const int qb = (grp ? (31 - p) : p) * 64;
    const u16* Qp = Q + (size_t)bh * SS * HD;
    const u16* Kp = K + (size_t)bh * SS * HD;
    const u16* Vp = V + (size_t)bh * HD * SS;   // transposed [d][s]
    const int srow = L >> 3;
    const int scg  = ((L & 7) ^ (L >> 3)) * 8;
    const int srcA = ln + 32 * (qd & 1);        // P-redistribution source lane

    const int ntile   = 32 - p;
    const int myTiles = grp ? ntile : (p + 1);

    bf16x8 qf[2];
    {
        const u16* rq = Qp + (size_t)(qb + wsub * 16 + ln) * HD;
        qf[0] = *(const bf16x8*)(rq + qd * 8);
        qf[1] = *(const bf16x8*)(rq + 32 + qd * 8);
    }

    f32x4 o[4];
    #pragma unroll
    for (int ni = 0; ni < 4; ++ni)
        #pragma unroll
        for (int e = 0; e < 4; ++e) o[ni][e] = 0.f;
    float m = -3.0e38f, l = 0.f;

    // ---- prologue: stage tile 0 (K: 8 waves x 8 rows; V^T: 8 waves x 8 d-rows) ----
    gld16(Kp + (size_t)(wv * 8 + srow) * HD + scg, &Ks[0][(wv * 8) * 64]);
    gld16(Vp + (size_t)(wv * 8 + srow) * SS + scg, &Vt[0][(wv * 8) * 64]);
    __syncthreads();

    for (int tix = 0; tix < ntile; ++tix) {
        const int j0 = tix * 64;
        const int buf = tix & 1;
        const bool more = (tix + 1 < ntile);

        // ---- prefetch tile t+1 async into buf^1 ----
        if (more) {
            const int j1 = j0 + 64;
            gld16(Kp + (size_t)(j1 + wv * 8 + srow) * HD + scg, &Ks[buf ^ 1][(wv * 8) * 64]);
            gld16(Vp + (size_t)(wv * 8 + srow) * SS + j1 + scg, &Vt[buf ^ 1][(wv * 8) * 64]);
        }

        if (tix < myTiles) {
            // ---- hoist ALL V fragments: PV depends only on P afterwards ----
            bf16x8 vf[2][4];
            #pragma unroll
            for (int kc = 0; kc < 2; ++kc)
                #pragma unroll
                for (int ni = 0; ni < 4; ++ni)
                    vf[kc][ni] = *(const bf16x8*)&Vt[buf][(ni * 16 + ln) * 64 + (((kc * 4 + qd) ^ (ln & 7)) * 8)];

            float m_old = m;
            bf16x8 pf0, pf1;
            group_step(Ks[buf], qf, tix == myTiles - 1,
                       qb + wsub * 16 + ln, j0, ln, qd, srcA, m, l, pf0, pf1);
            // o-rescale only when the slow path updated m (rare after first tile)
            if (m != m_old) {
                float alpha = exp2f((m_old - m) * CEXP);
                #pragma unroll
                for (int ni = 0; ni < 4; ++ni)
                    #pragma unroll
                    for (int r = 0; r < 4; ++r) o[ni][r] *= alpha;
            }
            __builtin_amdgcn_s_setprio(1);
            #pragma unroll
            for (int ni = 0; ni < 4; ++ni)
                o[ni] = __builtin_amdgcn_mfma_f32_16x16x32_bf16(vf[0][ni], pf0, o[ni], 0, 0, 0);
            #pragma unroll
            for (int ni = 0; ni < 4; ++ni)
                o[ni] = __builtin_amdgcn_mfma_f32_16x16x32_bf16(vf[1][ni], pf1, o[ni], 0, 0, 0);
            __builtin_amdgcn_s_setprio(0);
        }
        __syncthreads();
    }

    // ---- epilogue: normalize in-lane, write Y bf16 (b, s, d_model), 8B runs ----
    const int b = bh >> 4, h = bh & 15;
    const float inv = 1.f / l;
    const int sq = qb + wsub * 16 + ln;
    #pragma unroll
    for (int ni = 0; ni < 4; ++ni) {
        bf16x4 pk;
        #pragma unroll
        for (int r = 0; r < 4; ++r) pk[r] = (__bf16)(o[ni][r] * inv);
        *(bf16x4*)&Y[((size_t)(b * SS + sq)) * DM + h * HD + ni * 16 + qd * 4] = pk;
    }
}

extern "C" void kernel_launch(void* const* d_in, const int* in_sizes, int n_in,
                              void* d_out, int out_size, void* d_ws, size_t ws_size,
                              hipStream_t stream)
{
    const float* x        = (const float*)d_in[0];
    const int*   tp       = (const int*)d_in[1];
    const int*   use_rope = (const int*)d_in[2];
    const float* Wq       = (const float*)d_in[3];
    const float* Wk       = (const float*)d_in[4];
    const float* Wv       = (const float*)d_in[5];
    const float* Wo       = (const float*)d_in[6];
    const float* cosp     = (const float*)d_in[7];
    const float* sinp     = (const float*)d_in[8];
    float* out = (float*)d_out;

    char* ws = (char*)d_ws;
    const size_t MB = 1 << 20;
    u16* xb  = (u16*)(ws);
    u16* Wqb = (u16*)(ws + 8 * MB);
    u16* Wkb = (u16*)(ws + 10 * MB);
    u16* Wvb = (u16*)(ws + 12 * MB);
    u16* Wob = (u16*)(ws + 14 * MB);
    u16* Qb  = (u16*)(ws + 16 * MB);
    u16* Kb  = (u16*)(ws + 24 * MB);
    u16* Vb  = (u16*)(ws + 32 * MB);
    u16* Yb  = (u16*)(ws + 40 * MB);

    cast_all<<<8192, 256, 0, stream>>>(x, Wq, Wk, Wv, Wo, xb, Wqb, Wkb, Wvb, Wob);
    qkv_gemm<<<dim3(DM / 128, BB * SS / 128, 3), 256, 0, stream>>>(
        xb, Wqb, Wkb, Wvb, tp, cosp, sinp, use_rope, Qb, Kb, Vb);
    attn_kernel<<<dim3(BB * NH, 16), 512, 0, stream>>>(Qb, Kb, Vb, Yb);
    out_gemm<<<dim3(DM / 128, BB * SS / 128), 512, 0, stream>>>(Yb, Wob, out);
}

// Round 9
// 186.245 us; speedup vs baseline: 1.4093x; 1.0146x over previous
//
#include <hip/hip_runtime.h>
#include <math.h>

#define BB 2
#define SS 2048
#define DM 1024
#define NH 16
#define HD 64

typedef __attribute__((ext_vector_type(8))) __bf16 bf16x8;
typedef __attribute__((ext_vector_type(4))) __bf16 bf16x4;
typedef __attribute__((ext_vector_type(8))) unsigned short u16x8;
typedef __attribute__((ext_vector_type(4))) float f32x4;
typedef unsigned short u16;
typedef unsigned int u32;
typedef __attribute__((address_space(1))) unsigned int u32g;
typedef __attribute__((address_space(3))) unsigned int u32l;

#define CEXP 0.18033688011112042f   // 0.125 * log2(e)

static __device__ __forceinline__ u16 f2bf(float f) {
    __bf16 h = (__bf16)f;
    return __builtin_bit_cast(unsigned short, h);
}

// async global->LDS, 16B/lane; lds base wave-uniform, lane i lands at base + i*16B
static __device__ __forceinline__ void gld16(const u16* g, u16* l) {
    __builtin_amdgcn_global_load_lds((const u32g*)g, (u32l*)l, 16, 0, 0);
}

// ---------------- fused fp32 -> bf16 cast for x + 4 weights ----------------
__global__ __launch_bounds__(256)
void cast_all(const float* __restrict__ x,
              const float* __restrict__ wq, const float* __restrict__ wk,
              const float* __restrict__ wv, const float* __restrict__ wo,
              u16* __restrict__ xb, u16* __restrict__ wqb, u16* __restrict__ wkb,
              u16* __restrict__ wvb, u16* __restrict__ wob)
{
    const int N4X = (BB * SS * DM) / 4;   // 1048576
    const int N4W = (DM * DM) / 4;        // 262144
    int i = blockIdx.x * 256 + threadIdx.x;
    const float* src; u16* dst; int off;
    if (i < N4X) { src = x; dst = xb; off = i; }
    else {
        int i2 = i - N4X;
        int w = i2 >> 18;
        off = i2 & (N4W - 1);
        switch (w) {
            case 0:  src = wq; dst = wqb; break;
            case 1:  src = wk; dst = wkb; break;
            case 2:  src = wv; dst = wvb; break;
            default: src = wo; dst = wob; break;
        }
    }
    float4 v = ((const float4*)src)[off];
    ushort4 o;
    o.x = f2bf(v.x); o.y = f2bf(v.y); o.z = f2bf(v.z); o.w = f2bf(v.w);
    ((ushort4*)dst)[off] = o;
}

// ---------------- QKV projection: BK=64 swizzled gld16; fp32 RoPE; transposed epilogue ------
// z==0/1 -> Q/K in [b,h,s,d]; z==2 -> V written TRANSPOSED [b,h,d,s], direct from acc.
__global__ __launch_bounds__(256, 3)
void qkv_gemm(const u16* __restrict__ X,
              const u16* __restrict__ Wq, const u16* __restrict__ Wk,
              const u16* __restrict__ Wv,
              const int* __restrict__ tp, const float* __restrict__ cosp,
              const float* __restrict__ sinp, const int* __restrict__ use_rope,
              u16* __restrict__ Q, u16* __restrict__ K, u16* __restrict__ V)
{
    const u16* W; u16* dst;
    if (blockIdx.z == 0)      { W = Wq; dst = Q; }
    else if (blockIdx.z == 1) { W = Wk; dst = K; }
    else                      { W = Wv; dst = V; }

    __shared__ u16 SH[4 * 64 * 68];   // 34816 B: {As,Bs} during k-loop; Ts after (z<2)
    u16* As = SH;                     // 128 x 64
    u16* Bs = SH + 8192;              // 128 x 64
    const int t  = threadIdx.x;
    const int wv = t >> 6, L = t & 63, ln = L & 15, qd = L >> 4;
    const int i0 = blockIdx.y * 128, j0 = blockIdx.x * 128;
    const int wm = (wv >> 1) * 64, wn = (wv & 1) * 64;
    const int srow = L >> 3;
    const int scg  = ((L & 7) ^ (L >> 3)) * 8;

    f32x4 acc[4][4];
    #pragma unroll
    for (int a = 0; a < 4; ++a)
        #pragma unroll
        for (int b = 0; b < 4; ++b)
            #pragma unroll
            for (int e = 0; e < 4; ++e) acc[a][b][e] = 0.f;

    for (int k0 = 0; k0 < DM; k0 += 64) {
        __syncthreads();
        #pragma unroll
        for (int g = 0; g < 4; ++g) {
            int rb = wv * 32 + g * 8;
            gld16(X + (size_t)(i0 + rb + srow) * DM + k0 + scg, &As[rb * 64]);
            gld16(W + (size_t)(j0 + rb + srow) * DM + k0 + scg, &Bs[rb * 64]);
        }
        __syncthreads();
        bf16x8 a[4][2], b[4][2];
        #pragma unroll
        for (int mi = 0; mi < 4; ++mi)
            #pragma unroll
            for (int kd = 0; kd < 2; ++kd)
                a[mi][kd] = *(const bf16x8*)&As[(wm + mi * 16 + ln) * 64 + (((kd * 4 + qd) ^ (ln & 7)) * 8)];
        #pragma unroll
        for (int ni = 0; ni < 4; ++ni)
            #pragma unroll
            for (int kd = 0; kd < 2; ++kd)
                b[ni][kd] = *(const bf16x8*)&Bs[(wn + ni * 16 + ln) * 64 + (((kd * 4 + qd) ^ (ln & 7)) * 8)];
        #pragma unroll
        for (int kd = 0; kd < 2; ++kd)
            #pragma unroll
            for (int mi = 0; mi < 4; ++mi)
                #pragma unroll
                for (int ni = 0; ni < 4; ++ni)
                    acc[mi][ni] = __builtin_amdgcn_mfma_f32_16x16x32_bf16(a[mi][kd], b[ni][kd], acc[mi][ni], 0, 0, 0);
    }

    // ---- RoPE in fp32 on accumulators (lane pairs hold adjacent d) ----
    const int rope_on = (blockIdx.z < 2) ? use_rope[0] : 0;
    if (rope_on) {
        #pragma unroll
        for (int mi = 0; mi < 4; ++mi)
            #pragma unroll
            for (int r = 0; r < 4; ++r) {
                int gi = i0 + wm + mi * 16 + qd * 4 + r;
                int s = gi & 2047;
                int pos = tp[s];
                #pragma unroll
                for (int ni = 0; ni < 4; ++ni) {
                    int d = wn + ni * 16 + ln;
                    int dh = d & 63;
                    float c  = cosp[pos * 32 + (dh >> 1)];
                    float sn = sinp[pos * 32 + (dh >> 1)];
                    float v = acc[mi][ni][r];
                    float pv = __shfl_xor(v, 1);
                    acc[mi][ni][r] = (dh & 1) ? (v * c + pv * sn) : (v * c - pv * sn);
                }
            }
    }

    const int h  = blockIdx.x * 2 + (wv & 1);
    const int sb = i0 + wm;
    const int b_ = sb >> 11, s0 = sb & 2047;
    if (blockIdx.z < 2) {
        // ---- epilogue: per-wave LDS transpose, Q/K [b,h,s,d] coalesced rows ----
        __syncthreads();
        u16* Ts = SH + wv * (64 * 68);    // 64 rows (s) x 64 cols (d), stride 68
        #pragma unroll
        for (int mi = 0; mi < 4; ++mi)
            #pragma unroll
            for (int ni = 0; ni < 4; ++ni)
                #pragma unroll
                for (int r = 0; r < 4; ++r)
                    Ts[(mi * 16 + qd * 4 + r) * 68 + ni * 16 + ln] = f2bf(acc[mi][ni][r]);

        const int lrow = L >> 3, lcol = (L & 7) * 8;
        #pragma unroll
        for (int r2 = 0; r2 < 8; ++r2) {
            int row = lrow + r2 * 8;
            u16x8 val = *(const u16x8*)&Ts[row * 68 + lcol];
            *(u16x8*)&dst[(((size_t)(b_ * NH + h)) * SS + s0 + row) * HD + lcol] = val;
        }
    } else {
        // ---- V: direct transposed store [b,h,d,s] from acc (4 consecutive s per
        // thread at fixed d) — no LDS transpose, no barrier ----
        #pragma unroll
        for (int mi = 0; mi < 4; ++mi)
            #pragma unroll
            for (int ni = 0; ni < 4; ++ni) {
                bf16x4 pk;
                #pragma unroll
                for (int r = 0; r < 4; ++r) pk[r] = (__bf16)acc[mi][ni][r];
                *(bf16x4*)&dst[(((size_t)(b_ * NH + h)) * HD + ni * 16 + ln) * SS
                               + s0 + mi * 16 + qd * 4] = pk;
            }
    }
}

// ---------------- output projection: 128x128 tile, 8 waves, fp32 transposed epilogue ----
__global__ __launch_bounds__(512, 2)
void out_gemm(const u16* __restrict__ X, const u16* __restrict__ W,
              float* __restrict__ dst)
{
    __shared__ char SHB[73728];       // {As 16K, Bs 16K} k-loop; Ts 72K epilogue
    u16* As = (u16*)SHB;              // 128 x 64
    u16* Bs = (u16*)SHB + 8192;       // 128 x 64
    const int t  = threadIdx.x;
    const int wv = t >> 6, L = t & 63, ln = L & 15, qd = L >> 4;
    const int i0 = blockIdx.y * 128, j0 = blockIdx.x * 128;
    const int wm = (wv >> 2) * 64, wn = (wv & 3) * 32;   // 2x4 wave grid, 64x32 each
    const int srow = L >> 3;
    const int scg  = ((L & 7) ^ (L >> 3)) * 8;

    f32x4 acc[4][2];
    #pragma unroll
    for (int mi = 0; mi < 4; ++mi)
        #pragma unroll
        for (int ni = 0; ni < 2; ++ni)
            #pragma unroll
            for (int e = 0; e < 4; ++e) acc[mi][ni][e] = 0.f;

    for (int k0 = 0; k0 < DM; k0 += 64) {
        __syncthreads();
        #pragma unroll
        for (int g = 0; g < 2; ++g) {
            int rb = wv * 16 + g * 8;
            gld16(X + (size_t)(i0 + rb + srow) * DM + k0 + scg, &As[rb * 64]);
            gld16(W + (size_t)(j0 + rb + srow) * DM + k0 + scg, &Bs[rb * 64]);
        }
        __syncthreads();
        bf16x8 a[4][2], b[2][2];
        #pragma unroll
        for (int mi = 0; mi < 4; ++mi)
            #pragma unroll
            for (int kd = 0; kd < 2; ++kd)
                a[mi][kd] = *(const bf16x8*)&As[(wm + mi * 16 + ln) * 64 + (((kd * 4 + qd) ^ (ln & 7)) * 8)];
        #pragma unroll
        for (int ni = 0; ni < 2; ++ni)
            #pragma unroll
            for (int kd = 0; kd < 2; ++kd)
                b[ni][kd] = *(const bf16x8*)&Bs[(wn + ni * 16 + ln) * 64 + (((kd * 4 + qd) ^ (ln & 7)) * 8)];
        #pragma unroll
        for (int kd = 0; kd < 2; ++kd)
            #pragma unroll
            for (int mi = 0; mi < 4; ++mi)
                #pragma unroll
                for (int ni = 0; ni < 2; ++ni)
                    acc[mi][ni] = __builtin_amdgcn_mfma_f32_16x16x32_bf16(a[mi][kd], b[ni][kd], acc[mi][ni], 0, 0, 0);
    }

    __syncthreads();
    float* Ts = (float*)SHB + wv * (64 * 36);   // per-wave 64 rows x 32 cols, stride 36
    #pragma unroll
    for (int mi = 0; mi < 4; ++mi)
        #pragma unroll
        for (int ni = 0; ni < 2; ++ni)
            #pragma unroll
            for (int r = 0; r < 4; ++r)
                Ts[(mi * 16 + qd * 4 + r) * 36 + ni * 16 + ln] = acc[mi][ni][r];

    const int lrow = L >> 3, lch = L & 7;
    #pragma unroll
    for (int r2 = 0; r2 < 8; ++r2) {
        int row = lrow + r2 * 8;
        float4 v = *(const float4*)&Ts[row * 36 + lch * 4];
        *(float4*)&dst[(size_t)(i0 + wm + row) * DM + j0 + wn + lch * 4] = v;
    }
}

// ---------------- MFMA flash attention: wave-specialized pairs, O^T accumulation ----
// Round-5 proven structure (best measured: 48.4 us): waves 0-3 = q-tile p, waves
// 4-7 = q-tile 31-p. S^T = mfma(K,Q) puts q in lane; O^T = mfma(V^T, P) keeps q in
// lane. Defer-max speculative softmax, V-fragment hoist, s_setprio around MFMA
// clusters, complementary-duration p remap, Ps LDS round-trip (cheapest verified
// P-redistribution; shfl/bpermute variant measured WORSE, r7).
static __device__ __forceinline__ void group_step(
    const u16* KsB, const bf16x8 qf[2], u16* psw,
    bool diag, int rowg, int j0, int ln, int qd,
    float& m, float& l, bf16x8& pf0, bf16x8& pf1)
{
    const int pm = 2 * (ln & 7);     // even XOR mask over 8B granules
    f32x4 s[4];
    __builtin_amdgcn_s_setprio(1);
    #pragma unroll
    for (int mt = 0; mt < 4; ++mt) {
        bf16x8 a0 = *(const bf16x8*)&KsB[(mt * 16 + ln) * 64 + ((qd ^ (ln & 7)) * 8)];
        bf16x8 a1 = *(const bf16x8*)&KsB[(mt * 16 + ln) * 64 + (((4 + qd) ^ (ln & 7)) * 8)];
        #pragma unroll
        for (int e = 0; e < 4; ++e) s[mt][e] = 0.f;
        s[mt] = __builtin_amdgcn_mfma_f32_16x16x32_bf16(a0, qf[0], s[mt], 0, 0, 0);
        s[mt] = __builtin_amdgcn_mfma_f32_16x16x32_bf16(a1, qf[1], s[mt], 0, 0, 0);
    }
    __builtin_amdgcn_s_setprio(0);
    if (diag) {
        #pragma unroll
        for (int mt = 0; mt < 4; ++mt)
            #pragma unroll
            for (int r = 0; r < 4; ++r)
                if (j0 + mt * 16 + qd * 4 + r > rowg) s[mt][r] = -3.0e38f;
    }

    // ---- speculative P with OLD max (overlaps the reduce below via ILP) ----
    float p[16];
    float nmc = m * CEXP;
    #pragma unroll
    for (int mt = 0; mt < 4; ++mt)
        #pragma unroll
        for (int r = 0; r < 4; ++r)
            p[mt * 4 + r] = exp2f(fmaf(s[mt][r], CEXP, -nmc));

    // ---- row max (per-lane q) ----
    float rm = s[0][0];
    #pragma unroll
    for (int mt = 0; mt < 4; ++mt)
        #pragma unroll
        for (int r = 0; r < 4; ++r) rm = fmaxf(rm, s[mt][r]);
    rm = fmaxf(rm, __shfl_xor(rm, 16));
    rm = fmaxf(rm, __shfl_xor(rm, 32));

    // ---- slow path only when max grows materially (P bounded by 2^8) ----
    if (__any((rm - m) * CEXP > 8.0f)) {
        float nm = fmaxf(m, rm);
        float alpha = exp2f((m - nm) * CEXP);   // ==0 on first tile (m=-inf): l zeroed
        nmc = nm * CEXP;
        #pragma unroll
        for (int mt = 0; mt < 4; ++mt)
            #pragma unroll
            for (int r = 0; r < 4; ++r)
                p[mt * 4 + r] = exp2f(fmaf(s[mt][r], CEXP, -nmc));
        l *= alpha;
        m = nm;
    }

    // ---- pack + LDS round-trip + row sum ----
    float rs = 0.f;
    #pragma unroll
    for (int mt = 0; mt < 4; ++mt) {
        bf16x4 pk;
        #pragma unroll
        for (int r = 0; r < 4; ++r) {
            rs += p[mt * 4 + r];
            pk[r] = (__bf16)p[mt * 4 + r];
        }
        *(bf16x4*)(psw + ln * 64 + ((mt * 4 + qd) ^ pm) * 4) = pk;
    }
    rs += __shfl_xor(rs, 16);
    rs += __shfl_xor(rs, 32);
    l += rs;
    pf0 = *(const bf16x8*)(psw + ln * 64 + ((qd * 2) ^ pm) * 4);
    pf1 = *(const bf16x8*)(psw + ln * 64 + ((8 + qd * 2) ^ pm) * 4);
}

__global__ __launch_bounds__(512, 4)
void attn_kernel(const u16* __restrict__ Q, const u16* __restrict__ K,
                 const u16* __restrict__ V, u16* __restrict__ Y)
{
    __shared__ u16 Ks[2][64 * 64];     // [key][d], gld16 source-swizzled, double-buffered
    __shared__ u16 Vt[2][64 * 64];     // [d][key] from global V^T, gld16, double-buffered
    __shared__ u16 Ps[8][16 * 64];     // per-wave P round-trip, granule-swizzled

    const int t  = threadIdx.x;
    const int wv = t >> 6, L = t & 63, ln = L & 15, qd = L >> 4;
    const int wsub = wv & 3, grp = wv >> 2;
    const int bh = blockIdx.x;
    // complementary-duration remap: round-robin gives CU c blocks y and y+8 ->
    // p + p' = 15 -> every CU totals exactly 49 tile-iterations.
    const int y = blockIdx.y;
    const int p = (y < 8) ? y : (23 - y);
    const int qb = (grp ? (31 - p) : p) * 64;
    const u16* Qp = Q + (size_t)bh * SS * HD;
    const u16* Kp = K + (size_t)bh * SS * HD;
    const u16* Vp = V + (size_t)bh * HD * SS;   // transposed [d][s]
    const int srow = L >> 3;
    const int scg  = ((L & 7) ^ (L >> 3)) * 8;

    const int ntile   = 32 - p;
    const int myTiles = grp ? ntile : (p + 1);

    bf16x8 qf[2];
    {
        const u16* rq = Qp + (size_t)(qb + wsub * 16 + ln) * HD;
        qf[0] = *(const bf16x8*)(rq + qd * 8);
        qf[1] = *(const bf16x8*)(rq + 32 + qd * 8);
    }

    f32x4 o[4];
    #pragma unroll
    for (int ni = 0; ni < 4; ++ni)
        #pragma unroll
        for (int e = 0; e < 4; ++e) o[ni][e] = 0.f;
    float m = -3.0e38f, l = 0.f;

    // ---- prologue: stage tile 0 (K: 8 waves x 8 rows; V^T: 8 waves x 8 d-rows) ----
    gld16(Kp + (size_t)(wv * 8 + srow) * HD + scg, &Ks[0][(wv * 8) * 64]);
    gld16(Vp + (size_t)(wv * 8 + srow) * SS + scg, &Vt[0][(wv * 8) * 64]);
    __syncthreads();

    for (int tix = 0; tix < ntile; ++tix) {
        const int j0 = tix * 64;
        const int buf = tix & 1;
        const bool more = (tix + 1 < ntile);

        // ---- prefetch tile t+1 async into buf^1 ----
        if (more) {
            const int j1 = j0 + 64;
            gld16(Kp + (size_t)(j1 + wv * 8 + srow) * HD + scg, &Ks[buf ^ 1][(wv * 8) * 64]);
            gld16(Vp + (size_t)(wv * 8 + srow) * SS + j1 + scg, &Vt[buf ^ 1][(wv * 8) * 64]);
        }

        if (tix < myTiles) {
            // ---- hoist ALL V fragments: PV depends only on P afterwards ----
            bf16x8 vf[2][4];
            #pragma unroll
            for (int kc = 0; kc < 2; ++kc)
                #pragma unroll
                for (int ni = 0; ni < 4; ++ni)
                    vf[kc][ni] = *(const bf16x8*)&Vt[buf][(ni * 16 + ln) * 64 + (((kc * 4 + qd) ^ (ln & 7)) * 8)];

            float m_old = m;
            bf16x8 pf0, pf1;
            group_step(Ks[buf], qf, &Ps[wv][0], tix == myTiles - 1,
                       qb + wsub * 16 + ln, j0, ln, qd, m, l, pf0, pf1);
            // o-rescale only when the slow path updated m (rare after first tile)
            if (m != m_old) {
                float alpha = exp2f((m_old - m) * CEXP);
                #pragma unroll
                for (int ni = 0; ni < 4; ++ni)
                    #pragma unroll
                    for (int r = 0; r < 4; ++r) o[ni][r] *= alpha;
            }
            __builtin_amdgcn_s_setprio(1);
            #pragma unroll
            for (int ni = 0; ni < 4; ++ni)
                o[ni] = __builtin_amdgcn_mfma_f32_16x16x32_bf16(vf[0][ni], pf0, o[ni], 0, 0, 0);
            #pragma unroll
            for (int ni = 0; ni < 4; ++ni)
                o[ni] = __builtin_amdgcn_mfma_f32_16x16x32_bf16(vf[1][ni], pf1, o[ni], 0, 0, 0);
            __builtin_amdgcn_s_setprio(0);
        }
        __syncthreads();
    }

    // ---- epilogue: normalize in-lane, write Y bf16 (b, s, d_model), 8B runs ----
    const int b = bh >> 4, h = bh & 15;
    const float inv = 1.f / l;
    const int sq = qb + wsub * 16 + ln;
    #pragma unroll
    for (int ni = 0; ni < 4; ++ni) {
        bf16x4 pk;
        #pragma unroll
        for (int r = 0; r < 4; ++r) pk[r] = (__bf16)(o[ni][r] * inv);
        *(bf16x4*)&Y[((size_t)(b * SS + sq)) * DM + h * HD + ni * 16 + qd * 4] = pk;
    }
}

extern "C" void kernel_launch(void* const* d_in, const int* in_sizes, int n_in,
                              void* d_out, int out_size, void* d_ws, size_t ws_size,
                              hipStream_t stream)
{
    const float* x        = (const float*)d_in[0];
    const int*   tp       = (const int*)d_in[1];
    const int*   use_rope = (const int*)d_in[2];
    const float* Wq       = (const float*)d_in[3];
    const float* Wk       = (const float*)d_in[4];
    const float* Wv       = (const float*)d_in[5];
    const float* Wo       = (const float*)d_in[6];
    const float* cosp     = (const float*)d_in[7];
    const float* sinp     = (const float*)d_in[8];
    float* out = (float*)d_out;

    char* ws = (char*)d_ws;
    const size_t MB = 1 << 20;
    u16* xb  = (u16*)(ws);
    u16* Wqb = (u16*)(ws + 8 * MB);
    u16* Wkb = (u16*)(ws + 10 * MB);
    u16* Wvb = (u16*)(ws + 12 * MB);
    u16* Wob = (u16*)(ws + 14 * MB);
    u16* Qb  = (u16*)(ws + 16 * MB);
    u16* Kb  = (u16*)(ws + 24 * MB);
    u16* Vb  = (u16*)(ws + 32 * MB);
    u16* Yb  = (u16*)(ws + 40 * MB);

    cast_all<<<8192, 256, 0, stream>>>(x, Wq, Wk, Wv, Wo, xb, Wqb, Wkb, Wvb, Wob);
    qkv_gemm<<<dim3(DM / 128, BB * SS / 128, 3), 256, 0, stream>>>(
        xb, Wqb, Wkb, Wvb, tp, cosp, sinp, use_rope, Qb, Kb, Vb);
    attn_kernel<<<dim3(BB * NH, 16), 512, 0, stream>>>(Qb, Kb, Vb, Yb);
    out_gemm<<<dim3(DM / 128, BB * SS / 128), 512, 0, stream>>>(Yb, Wob, out);
}

// Round 10
// 177.318 us; speedup vs baseline: 1.4802x; 1.0503x over previous
//
#include <hip/hip_runtime.h>
#include <math.h>

#define BB 2
#define SS 2048
#define DM 1024
#define NH 16
#define HD 64

typedef __attribute__((ext_vector_type(8))) __bf16 bf16x8;
typedef __attribute__((ext_vector_type(4))) __bf16 bf16x4;
typedef __attribute__((ext_vector_type(8))) unsigned short u16x8;
typedef __attribute__((ext_vector_type(4))) float f32x4;
typedef unsigned short u16;
typedef unsigned int u32;
typedef __attribute__((address_space(1))) unsigned int u32g;
typedef __attribute__((address_space(3))) unsigned int u32l;

#define CEXP 0.18033688011112042f   // 0.125 * log2(e)

static __device__ __forceinline__ u16 f2bf(float f) {
    __bf16 h = (__bf16)f;
    return __builtin_bit_cast(unsigned short, h);
}

// async global->LDS, 16B/lane; lds base wave-uniform, lane i lands at base + i*16B
static __device__ __forceinline__ void gld16(const u16* g, u16* l) {
    __builtin_amdgcn_global_load_lds((const u32g*)g, (u32l*)l, 16, 0, 0);
}

// ---------------- fused fp32 -> bf16 cast for x + 4 weights ----------------
__global__ __launch_bounds__(256)
void cast_all(const float* __restrict__ x,
              const float* __restrict__ wq, const float* __restrict__ wk,
              const float* __restrict__ wv, const float* __restrict__ wo,
              u16* __restrict__ xb, u16* __restrict__ wqb, u16* __restrict__ wkb,
              u16* __restrict__ wvb, u16* __restrict__ wob)
{
    const int N4X = (BB * SS * DM) / 4;   // 1048576
    const int N4W = (DM * DM) / 4;        // 262144
    int i = blockIdx.x * 256 + threadIdx.x;
    const float* src; u16* dst; int off;
    if (i < N4X) { src = x; dst = xb; off = i; }
    else {
        int i2 = i - N4X;
        int w = i2 >> 18;
        off = i2 & (N4W - 1);
        switch (w) {
            case 0:  src = wq; dst = wqb; break;
            case 1:  src = wk; dst = wkb; break;
            case 2:  src = wv; dst = wvb; break;
            default: src = wo; dst = wob; break;
        }
    }
    float4 v = ((const float4*)src)[off];
    ushort4 o;
    o.x = f2bf(v.x); o.y = f2bf(v.y); o.z = f2bf(v.z); o.w = f2bf(v.w);
    ((ushort4*)dst)[off] = o;
}

// ---------------- QKV projection: BK=64 swizzled gld16; fp32 RoPE; transposed epilogue ------
// z==0/1 -> Q/K in [b,h,s,d]; z==2 -> V written TRANSPOSED [b,h,d,s], direct from acc.
__global__ __launch_bounds__(256, 3)
void qkv_gemm(const u16* __restrict__ X,
              const u16* __restrict__ Wq, const u16* __restrict__ Wk,
              const u16* __restrict__ Wv,
              const int* __restrict__ tp, const float* __restrict__ cosp,
              const float* __restrict__ sinp, const int* __restrict__ use_rope,
              u16* __restrict__ Q, u16* __restrict__ K, u16* __restrict__ V)
{
    const u16* W; u16* dst;
    if (blockIdx.z == 0)      { W = Wq; dst = Q; }
    else if (blockIdx.z == 1) { W = Wk; dst = K; }
    else                      { W = Wv; dst = V; }

    __shared__ u16 SH[4 * 64 * 68];   // 34816 B: {As,Bs} during k-loop; Ts after (z<2)
    u16* As = SH;                     // 128 x 64
    u16* Bs = SH + 8192;              // 128 x 64
    const int t  = threadIdx.x;
    const int wv = t >> 6, L = t & 63, ln = L & 15, qd = L >> 4;
    const int i0 = blockIdx.y * 128, j0 = blockIdx.x * 128;
    const int wm = (wv >> 1) * 64, wn = (wv & 1) * 64;
    const int srow = L >> 3;
    const int scg  = ((L & 7) ^ (L >> 3)) * 8;

    f32x4 acc[4][4];
    #pragma unroll
    for (int a = 0; a < 4; ++a)
        #pragma unroll
        for (int b = 0; b < 4; ++b)
            #pragma unroll
            for (int e = 0; e < 4; ++e) acc[a][b][e] = 0.f;

    for (int k0 = 0; k0 < DM; k0 += 64) {
        __syncthreads();
        #pragma unroll
        for (int g = 0; g < 4; ++g) {
            int rb = wv * 32 + g * 8;
            gld16(X + (size_t)(i0 + rb + srow) * DM + k0 + scg, &As[rb * 64]);
            gld16(W + (size_t)(j0 + rb + srow) * DM + k0 + scg, &Bs[rb * 64]);
        }
        __syncthreads();
        bf16x8 a[4][2], b[4][2];
        #pragma unroll
        for (int mi = 0; mi < 4; ++mi)
            #pragma unroll
            for (int kd = 0; kd < 2; ++kd)
                a[mi][kd] = *(const bf16x8*)&As[(wm + mi * 16 + ln) * 64 + (((kd * 4 + qd) ^ (ln & 7)) * 8)];
        #pragma unroll
        for (int ni = 0; ni < 4; ++ni)
            #pragma unroll
            for (int kd = 0; kd < 2; ++kd)
                b[ni][kd] = *(const bf16x8*)&Bs[(wn + ni * 16 + ln) * 64 + (((kd * 4 + qd) ^ (ln & 7)) * 8)];
        #pragma unroll
        for (int kd = 0; kd < 2; ++kd)
            #pragma unroll
            for (int mi = 0; mi < 4; ++mi)
                #pragma unroll
                for (int ni = 0; ni < 4; ++ni)
                    acc[mi][ni] = __builtin_amdgcn_mfma_f32_16x16x32_bf16(a[mi][kd], b[ni][kd], acc[mi][ni], 0, 0, 0);
    }

    // ---- RoPE in fp32 on accumulators (lane pairs hold adjacent d) ----
    const int rope_on = (blockIdx.z < 2) ? use_rope[0] : 0;
    if (rope_on) {
        #pragma unroll
        for (int mi = 0; mi < 4; ++mi)
            #pragma unroll
            for (int r = 0; r < 4; ++r) {
                int gi = i0 + wm + mi * 16 + qd * 4 + r;
                int s = gi & 2047;
                int pos = tp[s];
                #pragma unroll
                for (int ni = 0; ni < 4; ++ni) {
                    int d = wn + ni * 16 + ln;
                    int dh = d & 63;
                    float c  = cosp[pos * 32 + (dh >> 1)];
                    float sn = sinp[pos * 32 + (dh >> 1)];
                    float v = acc[mi][ni][r];
                    float pv = __shfl_xor(v, 1);
                    acc[mi][ni][r] = (dh & 1) ? (v * c + pv * sn) : (v * c - pv * sn);
                }
            }
    }

    const int h  = blockIdx.x * 2 + (wv & 1);
    const int sb = i0 + wm;
    const int b_ = sb >> 11, s0 = sb & 2047;
    if (blockIdx.z < 2) {
        // ---- epilogue: per-wave LDS transpose, Q/K [b,h,s,d] coalesced rows ----
        __syncthreads();
        u16* Ts = SH + wv * (64 * 68);    // 64 rows (s) x 64 cols (d), stride 68
        #pragma unroll
        for (int mi = 0; mi < 4; ++mi)
            #pragma unroll
            for (int ni = 0; ni < 4; ++ni)
                #pragma unroll
                for (int r = 0; r < 4; ++r)
                    Ts[(mi * 16 + qd * 4 + r) * 68 + ni * 16 + ln] = f2bf(acc[mi][ni][r]);

        const int lrow = L >> 3, lcol = (L & 7) * 8;
        #pragma unroll
        for (int r2 = 0; r2 < 8; ++r2) {
            int row = lrow + r2 * 8;
            u16x8 val = *(const u16x8*)&Ts[row * 68 + lcol];
            *(u16x8*)&dst[(((size_t)(b_ * NH + h)) * SS + s0 + row) * HD + lcol] = val;
        }
    } else {
        // ---- V: direct transposed store [b,h,d,s] from acc (4 consecutive s per
        // thread at fixed d) — no LDS transpose, no barrier ----
        #pragma unroll
        for (int mi = 0; mi < 4; ++mi)
            #pragma unroll
            for (int ni = 0; ni < 4; ++ni) {
                bf16x4 pk;
                #pragma unroll
                for (int r = 0; r < 4; ++r) pk[r] = (__bf16)acc[mi][ni][r];
                *(bf16x4*)&dst[(((size_t)(b_ * NH + h)) * HD + ni * 16 + ln) * SS
                               + s0 + mi * 16 + qd * 4] = pk;
            }
    }
}

// ---------------- output projection: 64x64 tile, 4 waves, 1024 blocks = 4/CU ----
// 128x128@256 blocks was 1 block/CU (8 barrier-correlated waves, ~170 TF implied).
// 64x64 gives 4 decorrelated blocks/CU (16 waves); staging is L2/L3-fed so the
// halved arithmetic intensity is paid in cache BW, not HBM.
__global__ __launch_bounds__(256, 4)
void out_gemm(const u16* __restrict__ X, const u16* __restrict__ W,
              float* __restrict__ dst)
{
    __shared__ char SHB[18432];       // {As 8K, Bs 8K} k-loop; Ts 18K epilogue
    u16* As = (u16*)SHB;              // 64 x 64
    u16* Bs = (u16*)SHB + 4096;       // 64 x 64
    const int t  = threadIdx.x;
    const int wv = t >> 6, L = t & 63, ln = L & 15, qd = L >> 4;
    const int i0 = blockIdx.y * 64, j0 = blockIdx.x * 64;
    const int wm = (wv >> 1) * 32, wn = (wv & 1) * 32;   // 2x2 wave grid, 32x32 each
    const int srow = L >> 3;
    const int scg  = ((L & 7) ^ (L >> 3)) * 8;

    f32x4 acc[2][2];
    #pragma unroll
    for (int mi = 0; mi < 2; ++mi)
        #pragma unroll
        for (int ni = 0; ni < 2; ++ni)
            #pragma unroll
            for (int e = 0; e < 4; ++e) acc[mi][ni][e] = 0.f;

    for (int k0 = 0; k0 < DM; k0 += 64) {
        __syncthreads();
        #pragma unroll
        for (int g = 0; g < 2; ++g) {
            int rb = wv * 16 + g * 8;
            gld16(X + (size_t)(i0 + rb + srow) * DM + k0 + scg, &As[rb * 64]);
            gld16(W + (size_t)(j0 + rb + srow) * DM + k0 + scg, &Bs[rb * 64]);
        }
        __syncthreads();
        bf16x8 a[2][2], b[2][2];
        #pragma unroll
        for (int mi = 0; mi < 2; ++mi)
            #pragma unroll
            for (int kd = 0; kd < 2; ++kd)
                a[mi][kd] = *(const bf16x8*)&As[(wm + mi * 16 + ln) * 64 + (((kd * 4 + qd) ^ (ln & 7)) * 8)];
        #pragma unroll
        for (int ni = 0; ni < 2; ++ni)
            #pragma unroll
            for (int kd = 0; kd < 2; ++kd)
                b[ni][kd] = *(const bf16x8*)&Bs[(wn + ni * 16 + ln) * 64 + (((kd * 4 + qd) ^ (ln & 7)) * 8)];
        #pragma unroll
        for (int kd = 0; kd < 2; ++kd)
            #pragma unroll
            for (int mi = 0; mi < 2; ++mi)
                #pragma unroll
                for (int ni = 0; ni < 2; ++ni)
                    acc[mi][ni] = __builtin_amdgcn_mfma_f32_16x16x32_bf16(a[mi][kd], b[ni][kd], acc[mi][ni], 0, 0, 0);
    }

    __syncthreads();
    float* Ts = (float*)SHB + wv * (32 * 36);   // per-wave 32 rows x 32 cols, stride 36
    #pragma unroll
    for (int mi = 0; mi < 2; ++mi)
        #pragma unroll
        for (int ni = 0; ni < 2; ++ni)
            #pragma unroll
            for (int r = 0; r < 4; ++r)
                Ts[(mi * 16 + qd * 4 + r) * 36 + ni * 16 + ln] = acc[mi][ni][r];

    const int lrow = L >> 3, lch = L & 7;
    #pragma unroll
    for (int r2 = 0; r2 < 4; ++r2) {
        int row = lrow + r2 * 8;
        float4 v = *(const float4*)&Ts[row * 36 + lch * 4];
        *(float4*)&dst[(size_t)(i0 + wm + row) * DM + j0 + wn + lch * 4] = v;
    }
}

// ---------------- MFMA flash attention: wave-specialized pairs, O^T accumulation ----
// Round-5 proven structure: waves 0-3 = q-tile p, waves 4-7 = q-tile 31-p.
// S^T = mfma(K,Q) puts q in lane; O^T = mfma(V^T, P) keeps q in lane. Defer-max
// speculative softmax, V-fragment hoist, s_setprio around MFMA clusters,
// complementary-duration p remap, Ps LDS round-trip (cheapest verified
// P-redistribution; shfl/bpermute variant measured WORSE, r7).
static __device__ __forceinline__ void group_step(
    const u16* KsB, const bf16x8 qf[2], u16* psw,
    bool diag, int rowg, int j0, int ln, int qd,
    float& m, float& l, bf16x8& pf0, bf16x8& pf1)
{
    const int pm = 2 * (ln & 7);     // even XOR mask over 8B granules
    f32x4 s[4];
    __builtin_amdgcn_s_setprio(1);
    #pragma unroll
    for (int mt = 0; mt < 4; ++mt) {
        bf16x8 a0 = *(const bf16x8*)&KsB[(mt * 16 + ln) * 64 + ((qd ^ (ln & 7)) * 8)];
        bf16x8 a1 = *(const bf16x8*)&KsB[(mt * 16 + ln) * 64 + (((4 + qd) ^ (ln & 7)) * 8)];
        #pragma unroll
        for (int e = 0; e < 4; ++e) s[mt][e] = 0.f;
        s[mt] = __builtin_amdgcn_mfma_f32_16x16x32_bf16(a0, qf[0], s[mt], 0, 0, 0);
        s[mt] = __builtin_amdgcn_mfma_f32_16x16x32_bf16(a1, qf[1], s[mt], 0, 0, 0);
    }
    __builtin_amdgcn_s_setprio(0);
    if (diag) {
        #pragma unroll
        for (int mt = 0; mt < 4; ++mt)
            #pragma unroll
            for (int r = 0; r < 4; ++r)
                if (j0 + mt * 16 + qd * 4 + r > rowg) s[mt][r] = -3.0e38f;
    }

    // ---- speculative P with OLD max (overlaps the reduce below via ILP) ----
    float p[16];
    float nmc = m * CEXP;
    #pragma unroll
    for (int mt = 0; mt < 4; ++mt)
        #pragma unroll
        for (int r = 0; r < 4; ++r)
            p[mt * 4 + r] = exp2f(fmaf(s[mt][r], CEXP, -nmc));

    // ---- row max (per-lane q) ----
    float rm = s[0][0];
    #pragma unroll
    for (int mt = 0; mt < 4; ++mt)
        #pragma unroll
        for (int r = 0; r < 4; ++r) rm = fmaxf(rm, s[mt][r]);
    rm = fmaxf(rm, __shfl_xor(rm, 16));
    rm = fmaxf(rm, __shfl_xor(rm, 32));

    // ---- slow path only when max grows materially (P bounded by 2^8) ----
    if (__any((rm - m) * CEXP > 8.0f)) {
        float nm = fmaxf(m, rm);
        float alpha = exp2f((m - nm) * CEXP);   // ==0 on first tile (m=-inf): l zeroed
        nmc = nm * CEXP;
        #pragma unroll
        for (int mt = 0; mt < 4; ++mt)
            #pragma unroll
            for (int r = 0; r < 4; ++r)
                p[mt * 4 + r] = exp2f(fmaf(s[mt][r], CEXP, -nmc));
        l *= alpha;
        m = nm;
    }

    // ---- pack + LDS round-trip + row sum ----
    float rs = 0.f;
    #pragma unroll
    for (int mt = 0; mt < 4; ++mt) {
        bf16x4 pk;
        #pragma unroll
        for (int r = 0; r < 4; ++r) {
            rs += p[mt * 4 + r];
            pk[r] = (__bf16)p[mt * 4 + r];
        }
        *(bf16x4*)(psw + ln * 64 + ((mt * 4 + qd) ^ pm) * 4) = pk;
    }
    rs += __shfl_xor(rs, 16);
    rs += __shfl_xor(rs, 32);
    l += rs;
    pf0 = *(const bf16x8*)(psw + ln * 64 + ((qd * 2) ^ pm) * 4);
    pf1 = *(const bf16x8*)(psw + ln * 64 + ((8 + qd * 2) ^ pm) * 4);
}

__global__ __launch_bounds__(512, 4)
void attn_kernel(const u16* __restrict__ Q, const u16* __restrict__ K,
                 const u16* __restrict__ V, u16* __restrict__ Y)
{
    __shared__ u16 Ks[2][64 * 64];     // [key][d], gld16 source-swizzled, double-buffered
    __shared__ u16 Vt[2][64 * 64];     // [d][key] from global V^T, gld16, double-buffered
    __shared__ u16 Ps[8][16 * 64];     // per-wave P round-trip, granule-swizzled

    const int t  = threadIdx.x;
    const int wv = t >> 6, L = t & 63, ln = L & 15, qd = L >> 4;
    const int wsub = wv & 3, grp = wv >> 2;
    const int bh = blockIdx.x;
    // complementary-duration remap: round-robin gives CU c blocks y and y+8 ->
    // p + p' = 15 -> every CU totals exactly 49 tile-iterations.
    const int y = blockIdx.y;
    const int p = (y < 8) ? y : (23 - y);
    const int qb = (grp ? (31 - p) : p) * 64;
    const u16* Qp = Q + (size_t)bh * SS * HD;
    const u16* Kp = K + (size_t)bh * SS * HD;
    const u16* Vp = V + (size_t)bh * HD * SS;   // transposed [d][s]
    const int srow = L >> 3;
    const int scg  = ((L & 7) ^ (L >> 3)) * 8;

    const int ntile   = 32 - p;
    const int myTiles = grp ? ntile : (p + 1);

    bf16x8 qf[2];
    {
        const u16* rq = Qp + (size_t)(qb + wsub * 16 + ln) * HD;
        qf[0] = *(const bf16x8*)(rq + qd * 8);
        qf[1] = *(const bf16x8*)(rq + 32 + qd * 8);
    }

    f32x4 o[4];
    #pragma unroll
    for (int ni = 0; ni < 4; ++ni)
        #pragma unroll
        for (int e = 0; e < 4; ++e) o[ni][e] = 0.f;
    float m = -3.0e38f, l = 0.f;

    // ---- prologue: stage tile 0 (K: 8 waves x 8 rows; V^T: 8 waves x 8 d-rows) ----
    gld16(Kp + (size_t)(wv * 8 + srow) * HD + scg, &Ks[0][(wv * 8) * 64]);
    gld16(Vp + (size_t)(wv * 8 + srow) * SS + scg, &Vt[0][(wv * 8) * 64]);
    __syncthreads();

    for (int tix = 0; tix < ntile; ++tix) {
        const int j0 = tix * 64;
        const int buf = tix & 1;
        const bool more = (tix + 1 < ntile);

        // ---- prefetch tile t+1 async into buf^1 ----
        if (more) {
            const int j1 = j0 + 64;
            gld16(Kp + (size_t)(j1 + wv * 8 + srow) * HD + scg, &Ks[buf ^ 1][(wv * 8) * 64]);
            gld16(Vp + (size_t)(wv * 8 + srow) * SS + j1 + scg, &Vt[buf ^ 1][(wv * 8) * 64]);
        }

        if (tix < myTiles) {
            // ---- hoist ALL V fragments: PV depends only on P afterwards ----
            bf16x8 vf[2][4];
            #pragma unroll
            for (int kc = 0; kc < 2; ++kc)
                #pragma unroll
                for (int ni = 0; ni < 4; ++ni)
                    vf[kc][ni] = *(const bf16x8*)&Vt[buf][(ni * 16 + ln) * 64 + (((kc * 4 + qd) ^ (ln & 7)) * 8)];

            float m_old = m;
            bf16x8 pf0, pf1;
            group_step(Ks[buf], qf, &Ps[wv][0], tix == myTiles - 1,
                       qb + wsub * 16 + ln, j0, ln, qd, m, l, pf0, pf1);
            // o-rescale only when the slow path updated m (rare after first tile)
            if (m != m_old) {
                float alpha = exp2f((m_old - m) * CEXP);
                #pragma unroll
                for (int ni = 0; ni < 4; ++ni)
                    #pragma unroll
                    for (int r = 0; r < 4; ++r) o[ni][r] *= alpha;
            }
            __builtin_amdgcn_s_setprio(1);
            #pragma unroll
            for (int ni = 0; ni < 4; ++ni)
                o[ni] = __builtin_amdgcn_mfma_f32_16x16x32_bf16(vf[0][ni], pf0, o[ni], 0, 0, 0);
            #pragma unroll
            for (int ni = 0; ni < 4; ++ni)
                o[ni] = __builtin_amdgcn_mfma_f32_16x16x32_bf16(vf[1][ni], pf1, o[ni], 0, 0, 0);
            __builtin_amdgcn_s_setprio(0);
        }
        __syncthreads();
    }

    // ---- epilogue: normalize in-lane, write Y bf16 (b, s, d_model), 8B runs ----
    const int b = bh >> 4, h = bh & 15;
    const float inv = 1.f / l;
    const int sq = qb + wsub * 16 + ln;
    #pragma unroll
    for (int ni = 0; ni < 4; ++ni) {
        bf16x4 pk;
        #pragma unroll
        for (int r = 0; r < 4; ++r) pk[r] = (__bf16)(o[ni][r] * inv);
        *(bf16x4*)&Y[((size_t)(b * SS + sq)) * DM + h * HD + ni * 16 + qd * 4] = pk;
    }
}

extern "C" void kernel_launch(void* const* d_in, const int* in_sizes, int n_in,
                              void* d_out, int out_size, void* d_ws, size_t ws_size,
                              hipStream_t stream)
{
    const float* x        = (const float*)d_in[0];
    const int*   tp       = (const int*)d_in[1];
    const int*   use_rope = (const int*)d_in[2];
    const float* Wq       = (const float*)d_in[3];
    const float* Wk       = (const float*)d_in[4];
    const float* Wv       = (const float*)d_in[5];
    const float* Wo       = (const float*)d_in[6];
    const float* cosp     = (const float*)d_in[7];
    const float* sinp     = (const float*)d_in[8];
    float* out = (float*)d_out;

    char* ws = (char*)d_ws;
    const size_t MB = 1 << 20;
    u16* xb  = (u16*)(ws);
    u16* Wqb = (u16*)(ws + 8 * MB);
    u16* Wkb = (u16*)(ws + 10 * MB);
    u16* Wvb = (u16*)(ws + 12 * MB);
    u16* Wob = (u16*)(ws + 14 * MB);
    u16* Qb  = (u16*)(ws + 16 * MB);
    u16* Kb  = (u16*)(ws + 24 * MB);
    u16* Vb  = (u16*)(ws + 32 * MB);
    u16* Yb  = (u16*)(ws + 40 * MB);

    cast_all<<<8192, 256, 0, stream>>>(x, Wq, Wk, Wv, Wo, xb, Wqb, Wkb, Wvb, Wob);
    qkv_gemm<<<dim3(DM / 128, BB * SS / 128, 3), 256, 0, stream>>>(
        xb, Wqb, Wkb, Wvb, tp, cosp, sinp, use_rope, Qb, Kb, Vb);
    attn_kernel<<<dim3(BB * NH, 16), 512, 0, stream>>>(Qb, Kb, Vb, Yb);
    out_gemm<<<dim3(DM / 64, BB * SS / 64), 256, 0, stream>>>(Yb, Wob, out);
}